// Round 12
// baseline (176.153 us; speedup 1.0000x reference)
//
#include <hip/hip_runtime.h>

#define BATCH 32
#define CH    256
#define HWPX  3136   // 56*56
#define WIDTH 56
#define NK    16
#define NSLAB 28     // kpmat pixel slabs per batch (112 px each)
#define WGTS  52     // wgt row stride (49 padded to 13*float4)
#define EPSV  1e-5f

// ---------------------------------------------------------------------------
// Kernel 1: K-partials. Kpart[s][b,n,k] = sum_{c in sub s} k_w[k,c]*BN(x[b,c,n])
// R11 lesson: kkvec was GRID-limited (784 blocks = 3.06 waves/SIMD; occupancy
// 29% vs 38% ceiling; VALUBusy 15%). Fix: NS=8 channel split -> 1568 blocks,
// 6.1 waves/SIMD; per-thread channels 64->32. Runtime-gated on ws_size
// (Kpart doubles to 51.4MB); falls back to proven NS=4.
// ---------------------------------------------------------------------------
template<int NS>
__global__ __launch_bounds__(256, 6) void kkvec(
    const float* __restrict__ x,
    const float* __restrict__ gamma, const float* __restrict__ beta,
    const float* __restrict__ mean,  const float* __restrict__ var,
    const float* __restrict__ kw,    float* __restrict__ Kpart)
{
    constexpr int CSUB = CH / NS;               // channels per sub
    const int sub = blockIdx.x / 196;           // 0..NS-1, block-uniform
    const int pb  = blockIdx.x % 196;
    const int job = pb * 256 + threadIdx.x;     // 0..50175 = b*1568 + px2
    const int b   = job / 1568;
    const int px2 = job % 1568;                 // float2 index in plane
    const int cbase = sub * CSUB;
    const float* xp = x + ((size_t)b * CH + cbase) * HWPX + px2 * 2;

    float acc0[NK], acc1[NK];
#pragma unroll
    for (int k = 0; k < NK; ++k) { acc0[k] = 0.f; acc1[k] = 0.f; }

    for (int c0 = 0; c0 < CSUB; c0 += 8) {
        float2 v[8];
#pragma unroll
        for (int i = 0; i < 8; ++i)             // 8 x 512B wave-loads in flight
            v[i] = *(const float2*)(xp + (size_t)(c0 + i) * HWPX);
#pragma unroll
        for (int i = 0; i < 8; ++i) {           // BN (params wave-uniform)
            const int c = cbase + c0 + i;
            const float sc = gamma[c] * rsqrtf(var[c] + EPSV);
            const float sh = fmaf(-mean[c], sc, beta[c]);
            v[i].x = fmaf(v[i].x, sc, sh);
            v[i].y = fmaf(v[i].y, sc, sh);
        }
#pragma unroll
        for (int k = 0; k < NK; ++k) {
            const float4 w0 = *(const float4*)(kw + k * CH + cbase + c0);     // uniform
            const float4 w1 = *(const float4*)(kw + k * CH + cbase + c0 + 4); // uniform
            acc0[k] = fmaf(v[0].x, w0.x, acc0[k]); acc1[k] = fmaf(v[0].y, w0.x, acc1[k]);
            acc0[k] = fmaf(v[1].x, w0.y, acc0[k]); acc1[k] = fmaf(v[1].y, w0.y, acc1[k]);
            acc0[k] = fmaf(v[2].x, w0.z, acc0[k]); acc1[k] = fmaf(v[2].y, w0.z, acc1[k]);
            acc0[k] = fmaf(v[3].x, w0.w, acc0[k]); acc1[k] = fmaf(v[3].y, w0.w, acc1[k]);
            acc0[k] = fmaf(v[4].x, w1.x, acc0[k]); acc1[k] = fmaf(v[4].y, w1.x, acc1[k]);
            acc0[k] = fmaf(v[5].x, w1.y, acc0[k]); acc1[k] = fmaf(v[5].y, w1.y, acc1[k]);
            acc0[k] = fmaf(v[6].x, w1.z, acc0[k]); acc1[k] = fmaf(v[6].y, w1.z, acc1[k]);
            acc0[k] = fmaf(v[7].x, w1.w, acc0[k]); acc1[k] = fmaf(v[7].y, w1.w, acc1[k]);
        }
    }

    float* op = Kpart + ((size_t)sub * BATCH * HWPX + (size_t)b * HWPX + px2 * 2) * NK;
#pragma unroll
    for (int kq = 0; kq < 4; ++kq)
        ((float4*)op)[kq] = make_float4(acc0[kq*4+0], acc0[kq*4+1], acc0[kq*4+2], acc0[kq*4+3]);
#pragma unroll
    for (int kq = 0; kq < 4; ++kq)
        ((float4*)op)[4+kq] = make_float4(acc1[kq*4+0], acc1[kq*4+1], acc1[kq*4+2], acc1[kq*4+3]);
}

// ---------------------------------------------------------------------------
// Kernel 1b: K = sum of NS Kpart planes. float4 jobs, fully coalesced.
// ---------------------------------------------------------------------------
template<int NS>
__global__ __launch_bounds__(256) void ksum(
    const float* __restrict__ Kpart, float* __restrict__ Kbuf)
{
    const int i = blockIdx.x * 256 + threadIdx.x;   // 0..401407 float4 jobs
    const float4* p = (const float4*)Kpart;
    float4 s = p[i];
#pragma unroll
    for (int s2 = 1; s2 < NS; ++s2) {
        const float4 v = p[(size_t)s2 * 401408 + i];
        s.x += v.x; s.y += v.y; s.z += v.z; s.w += v.w;
    }
    ((float4*)Kbuf)[i] = s;
}

// ---------------------------------------------------------------------------
// Kernel 2: P_part[b,nb,c,k] = sum_{n in 112-px slab} BN(x[b,c,n]) * K[b,n,k]
// grid: 32*28 blocks, 256 threads; thread = channel row (14 waves/CU).
// ---------------------------------------------------------------------------
__global__ __launch_bounds__(256) void kpmat(
    const float* __restrict__ x,
    const float* __restrict__ gamma, const float* __restrict__ beta,
    const float* __restrict__ mean,  const float* __restrict__ var,
    const float* __restrict__ Kbuf,  float* __restrict__ Pp)
{
    const int b  = blockIdx.x / NSLAB;
    const int nb = blockIdx.x % NSLAB;
    const int n0 = nb * 112;
    const int c  = threadIdx.x;

    const float sc = gamma[c] * rsqrtf(var[c] + EPSV);
    const float sh = fmaf(-mean[c], sc, beta[c]);

    const float4* xr = (const float4*)(x + ((size_t)b * CH + c) * HWPX + n0);
    const float*  Kp = Kbuf + ((size_t)b * HWPX + n0) * NK;

    float acc[NK];
#pragma unroll
    for (int k = 0; k < NK; ++k) acc[k] = 0.f;

#pragma unroll 4
    for (int j = 0; j < 28; ++j) {
        const float4 xv = xr[j];
        float v[4];
        v[0] = fmaf(xv.x, sc, sh); v[1] = fmaf(xv.y, sc, sh);
        v[2] = fmaf(xv.z, sc, sh); v[3] = fmaf(xv.w, sc, sh);
#pragma unroll
        for (int d = 0; d < 4; ++d) {
            const float vd = v[d];
#pragma unroll
            for (int kq = 0; kq < 4; ++kq) {
                const float4 kv = *(const float4*)(Kp + ((j*4 + d) * NK) + kq*4); // uniform
                acc[kq*4+0] = fmaf(vd, kv.x, acc[kq*4+0]);
                acc[kq*4+1] = fmaf(vd, kv.y, acc[kq*4+1]);
                acc[kq*4+2] = fmaf(vd, kv.z, acc[kq*4+2]);
                acc[kq*4+3] = fmaf(vd, kv.w, acc[kq*4+3]);
            }
        }
    }
    float4* op = (float4*)(Pp + (((size_t)b * NSLAB + nb) * CH + c) * NK);
#pragma unroll
    for (int kq = 0; kq < 4; ++kq)
        op[kq] = make_float4(acc[kq*4+0], acc[kq*4+1], acc[kq*4+2], acc[kq*4+3]);
}

// ---------------------------------------------------------------------------
// Kernel 2b: reduce slab partials Pp[b][28][CH*NK] -> P[b][CH*NK]
// ---------------------------------------------------------------------------
__global__ __launch_bounds__(256) void kpred(
    const float* __restrict__ Pp, float* __restrict__ P)
{
    const int idx = blockIdx.x * 256 + threadIdx.x;   // 32*4096 total
    const int b = idx >> 12;
    const int e = idx & 4095;
    const float* p = Pp + (size_t)b * NSLAB * 4096 + e;
    float s = 0.f;
#pragma unroll
    for (int nb = 0; nb < NSLAB; ++nb) s += p[(size_t)nb * 4096];
    P[idx] = s;
}

// ---------------------------------------------------------------------------
// Kernel 3: S = q_w @ P; attn = softmax(S/512) over k; wgt = attn @ bank.
// wgt rows padded to 52 floats (16B-aligned float4 reads in kconv).
// ---------------------------------------------------------------------------
__global__ __launch_bounds__(256) void ksoft(
    const float* __restrict__ P, const float* __restrict__ qw,
    const float* __restrict__ bank, float* __restrict__ wgt)
{
    const int b  = blockIdx.x >> 3;
    const int cb = blockIdx.x & 7;
    const int tid = threadIdx.x;

    __shared__ float s_P[CH * NK];       // full P[b] (16 KB)
    __shared__ float s_red[32 * 8 * NK]; // partial S (16 KB)
    __shared__ float s_S[32 * NK];
    __shared__ float s_attn[32 * NK];

    for (int idx = tid; idx < CH * NK; idx += 256)
        s_P[idx] = P[(size_t)b * CH * NK + idx];
    __syncthreads();

    const int c_l = tid & 31, sub = tid >> 5;
    const int c = cb * 32 + c_l;
    float a[NK];
#pragma unroll
    for (int k = 0; k < NK; ++k) a[k] = 0.f;
    const float* qrow = qw + (size_t)c * CH + sub * 32;
    for (int j = 0; j < 32; ++j) {
        const float qv = qrow[j];
        const float4* p4 = (const float4*)&s_P[(sub * 32 + j) * NK];
#pragma unroll
        for (int kq = 0; kq < 4; ++kq) {
            const float4 pv = p4[kq];
            a[kq*4+0] = fmaf(qv, pv.x, a[kq*4+0]);
            a[kq*4+1] = fmaf(qv, pv.y, a[kq*4+1]);
            a[kq*4+2] = fmaf(qv, pv.z, a[kq*4+2]);
            a[kq*4+3] = fmaf(qv, pv.w, a[kq*4+3]);
        }
    }
#pragma unroll
    for (int kq = 0; kq < 4; ++kq)
        *(float4*)&s_red[(c_l * 8 + sub) * NK + kq*4] =
            make_float4(a[kq*4+0], a[kq*4+1], a[kq*4+2], a[kq*4+3]);
    __syncthreads();

    for (int idx = tid; idx < 32 * NK; idx += 256) {
        const int cl = idx >> 4, k = idx & 15;
        float s = 0.f;
#pragma unroll
        for (int s2 = 0; s2 < 8; ++s2) s += s_red[(cl * 8 + s2) * NK + k];
        s_S[idx] = s * (1.f / 512.f);
    }
    __syncthreads();

    if (tid < 32) {
        float l[NK];
#pragma unroll
        for (int k = 0; k < NK; ++k) l[k] = s_S[tid * NK + k];
        float m = l[0];
#pragma unroll
        for (int k = 1; k < NK; ++k) m = fmaxf(m, l[k]);
        float sum = 0.f;
#pragma unroll
        for (int k = 0; k < NK; ++k) { l[k] = __expf(l[k] - m); sum += l[k]; }
        const float inv = 1.f / sum;
#pragma unroll
        for (int k = 0; k < NK; ++k) s_attn[tid * NK + k] = l[k] * inv;
    }
    __syncthreads();

    for (int idx = tid; idx < 32 * 49; idx += 256) {
        const int cl = idx / 49, e = idx - cl * 49;
        float wv = 0.f;
#pragma unroll
        for (int k = 0; k < NK; ++k)
            wv = fmaf(s_attn[cl * NK + k], bank[k * 49 + e], wv);
        wgt[((size_t)b * CH + cb * 32 + cl) * WGTS + e] = wv;
    }
}

// ---------------------------------------------------------------------------
// Kernel 4: depthwise 7x7 'same' conv — zero-LDS, shuffle-halo line buffer.
// (R10-fixed: no min-waves arg -> no VGPR cap -> no spill.)
// Slot schedule (R9-verified): reset slot j%7 at TOP of iteration j.
// ---------------------------------------------------------------------------
__global__ __launch_bounds__(256) void kconv(
    const float* __restrict__ x, const float* __restrict__ wgt,
    const float* __restrict__ bias, float* __restrict__ out)
{
    const int t  = threadIdx.x;          // 0..255
    const int pl = t >> 4;               // 0..15 local plane
    const int q  = t & 15;               // 0..15 strip slot (14 valid)
    const int qc = q < 14 ? q : 13;      // clamped col chunk for idle lanes
    const int h  = blockIdx.x & 1;       // y-half
    const int plane = (blockIdx.x >> 1) * 16 + pl;
    const int ho = h * 28;               // first output row (0 or 28; ==0 mod 7)
    const bool qlo = (q == 0), qhi = (q >= 13);
    const float bv = bias[plane & 255];

    float4 wv[13];
    const float4* wp4 = (const float4*)(wgt + (size_t)plane * WGTS);
#pragma unroll
    for (int i = 0; i < 13; ++i) wv[i] = wp4[i];
#define WTAP(idx) ((idx)%4==0 ? wv[(idx)/4].x : (idx)%4==1 ? wv[(idx)/4].y : \
                   (idx)%4==2 ? wv[(idx)/4].z : wv[(idx)/4].w)

    const float* xrow = x   + (size_t)plane * HWPX + 4 * qc;
    float*       orow = out + (size_t)plane * HWPX + 4 * qc;

    float a[7][4];
#pragma unroll
    for (int i = 0; i < 7; ++i)
#pragma unroll
        for (int ix = 0; ix < 4; ++ix) a[i][ix] = bv;

    const float4 z4 = make_float4(0.f, 0.f, 0.f, 0.f);
    int ir0 = ho - 3;
    float4 vc = (0 <= ir0 && ir0 < 56) ? *(const float4*)(xrow + ir0 * WIDTH) : z4;

#pragma unroll 7
    for (int j = 0; j < 35; ++j) {
        const int snew = j % 7;                  // static under unroll 7
#pragma unroll
        for (int ix = 0; ix < 4; ++ix) a[snew][ix] = bv;

        const int irn = ho - 3 + j + 1;
        float4 vn = (0 <= irn && irn < 56 && j + 1 < 35)
                        ? *(const float4*)(xrow + irn * WIDTH) : z4;

        float rr1 = __shfl_up(vc.y, 1), rr2 = __shfl_up(vc.z, 1), rr3 = __shfl_up(vc.w, 1);
        float rr8 = __shfl_down(vc.x, 1), rr9 = __shfl_down(vc.y, 1), rr10 = __shfl_down(vc.z, 1);
        float rr[11];
        rr[1] = qlo ? 0.f : rr1;  rr[2] = qlo ? 0.f : rr2;  rr[3] = qlo ? 0.f : rr3;
        rr[4] = vc.x; rr[5] = vc.y; rr[6] = vc.z; rr[7] = vc.w;
        rr[8] = qhi ? 0.f : rr8;  rr[9] = qhi ? 0.f : rr9;  rr[10] = qhi ? 0.f : rr10;

#pragma unroll
        for (int i = 0; i < 7; ++i) {
            const int ky = 6 - i;
            const int s  = (j + i + 1) % 7;      // static (j%7 known by unroll)
#pragma unroll
            for (int kx = 0; kx < 7; ++kx) {
                const float wk = WTAP(ky * 7 + kx);
#pragma unroll
                for (int ix = 0; ix < 4; ++ix)
                    a[s][ix] = fmaf(wk, rr[ix + kx + 1], a[s][ix]);
            }
        }

        if (j >= 6 && j < 34) {                  // output row o = ho+j-6 done
            const int o  = ho + j - 6;
            const int sd = (j + 1) % 7;          // static; next iter resets it
            if (q < 14)
                *(float4*)(orow + o * WIDTH) =
                    make_float4(a[sd][0], a[sd][1], a[sd][2], a[sd][3]);
        }
        vc = vn;
    }
#undef WTAP
}

// ---------------------------------------------------------------------------
extern "C" void kernel_launch(void* const* d_in, const int* in_sizes, int n_in,
                              void* d_out, int out_size, void* d_ws, size_t ws_size,
                              hipStream_t stream)
{
    const float* x     = (const float*)d_in[0];
    const float* gamma = (const float*)d_in[1];
    const float* beta  = (const float*)d_in[2];
    const float* mean  = (const float*)d_in[3];
    const float* var   = (const float*)d_in[4];
    const float* qw    = (const float*)d_in[5];
    const float* kw    = (const float*)d_in[6];
    const float* bank  = (const float*)d_in[7];
    const float* bias  = (const float*)d_in[8];
    float* out = (float*)d_out;

    const size_t KPLANE = (size_t)BATCH * HWPX * NK;     // 1,605,632 f per sub
    const size_t tail   = KPLANE                          // Kbuf
                        + (size_t)BATCH * CH * NK         // P
                        + (size_t)BATCH * CH * WGTS;      // wgt
    const size_t need8  = (8 * KPLANE + tail) * sizeof(float);   // ~60 MB

    float* ws = (float*)d_ws;
    const int NS = (ws_size >= need8) ? 8 : 4;

    float* Kpart = ws;                       // NS * KPLANE floats
    float* Pp    = ws;                       // alias (Kpart dead after ksum)
    float* Kbuf  = ws + (size_t)NS * KPLANE;
    float* P     = Kbuf + KPLANE;
    float* wgt   = P + (size_t)BATCH * CH * NK;

    if (NS == 8) {
        kkvec<8><<<dim3(8 * 196), dim3(256), 0, stream>>>(x, gamma, beta, mean, var, kw, Kpart);
        ksum<8> <<<dim3(1568),    dim3(256), 0, stream>>>(Kpart, Kbuf);
    } else {
        kkvec<4><<<dim3(4 * 196), dim3(256), 0, stream>>>(x, gamma, beta, mean, var, kw, Kpart);
        ksum<4> <<<dim3(1568),    dim3(256), 0, stream>>>(Kpart, Kbuf);
    }
    kpmat<<<dim3(BATCH * NSLAB), dim3(256), 0, stream>>>(x, gamma, beta, mean, var, Kbuf, Pp);
    kpred<<<dim3(512),           dim3(256), 0, stream>>>(Pp, P);
    ksoft<<<dim3(BATCH * 8),     dim3(256), 0, stream>>>(P, qw, bank, wgt);
    kconv<<<dim3(BATCH * CH / 8),dim3(256), 0, stream>>>(x, wgt, bias, out);
}

// Round 13
// 151.146 us; speedup vs baseline: 1.1654x; 1.1654x over previous
//
#include <hip/hip_runtime.h>

#define BATCH 32
#define CH    256
#define HWPX  3136   // 56*56
#define WIDTH 56
#define NK    16
#define NSLAB 28     // kpmat pixel slabs per batch (112 px each)
#define NSUB  4      // kkvec channel split (NS=8 broke L3 residency, R12)
#define WGTS  52     // wgt row stride (49 padded to 13*float4)
#define EPSV  1e-5f

// ---------------------------------------------------------------------------
// Kernel 1: K-partials. Kpart[s][b,n,k] = sum_{c in sub s} k_w[k,c]*BN(x[b,c,n])
// R12 lesson: NS=8 pushed workspace past L3 (x+out+Kpart > 256MB) -> 3.2x
// write amplification, 97us. Stay NS=4 (writes exactly 25.7MB, L3-resident).
// R13: attack latency-serialization instead (VALUBusy was 15%): explicit
// register double-buffer — issue batch c0+8's 8 loads BEFORE computing batch
// c0, so HBM latency hides under the 512-cy FMA block. Full unroll makes the
// cur<-nxt swap free (renaming). No launch_bounds arg2 (R10: caps VGPR ~2x
// tighter than 512/w; demand here ~90).
// ---------------------------------------------------------------------------
__global__ __launch_bounds__(256) void kkvec(
    const float* __restrict__ x,
    const float* __restrict__ gamma, const float* __restrict__ beta,
    const float* __restrict__ mean,  const float* __restrict__ var,
    const float* __restrict__ kw,    float* __restrict__ Kpart)
{
    const int sub = blockIdx.x / 196;           // 0..3, block-uniform
    const int pb  = blockIdx.x % 196;
    const int job = pb * 256 + threadIdx.x;     // 0..50175 = b*1568 + px2
    const int b   = job / 1568;
    const int px2 = job % 1568;                 // float2 index in plane
    const int cbase = sub * 64;
    const float* xp = x + ((size_t)b * CH + cbase) * HWPX + px2 * 2;

    float acc0[NK], acc1[NK];
#pragma unroll
    for (int k = 0; k < NK; ++k) { acc0[k] = 0.f; acc1[k] = 0.f; }

    float2 cur[8], nxt[8];
#pragma unroll
    for (int i = 0; i < 8; ++i)                 // prime the pipeline
        cur[i] = *(const float2*)(xp + (size_t)i * HWPX);

#pragma unroll
    for (int c0 = 0; c0 < 64; c0 += 8) {
        // issue next batch's loads first (overlap with compute below)
        if (c0 + 8 < 64) {
#pragma unroll
            for (int i = 0; i < 8; ++i)
                nxt[i] = *(const float2*)(xp + (size_t)(c0 + 8 + i) * HWPX);
        }
        // BN (params wave-uniform -> scalar loads)
        float2 v[8];
#pragma unroll
        for (int i = 0; i < 8; ++i) {
            const int c = cbase + c0 + i;
            const float sc = gamma[c] * rsqrtf(var[c] + EPSV);
            const float sh = fmaf(-mean[c], sc, beta[c]);
            v[i].x = fmaf(cur[i].x, sc, sh);
            v[i].y = fmaf(cur[i].y, sc, sh);
        }
#pragma unroll
        for (int k = 0; k < NK; ++k) {
            const float4 w0 = *(const float4*)(kw + k * CH + cbase + c0);     // uniform
            const float4 w1 = *(const float4*)(kw + k * CH + cbase + c0 + 4); // uniform
            acc0[k] = fmaf(v[0].x, w0.x, acc0[k]); acc1[k] = fmaf(v[0].y, w0.x, acc1[k]);
            acc0[k] = fmaf(v[1].x, w0.y, acc0[k]); acc1[k] = fmaf(v[1].y, w0.y, acc1[k]);
            acc0[k] = fmaf(v[2].x, w0.z, acc0[k]); acc1[k] = fmaf(v[2].y, w0.z, acc1[k]);
            acc0[k] = fmaf(v[3].x, w0.w, acc0[k]); acc1[k] = fmaf(v[3].y, w0.w, acc1[k]);
            acc0[k] = fmaf(v[4].x, w1.x, acc0[k]); acc1[k] = fmaf(v[4].y, w1.x, acc1[k]);
            acc0[k] = fmaf(v[5].x, w1.y, acc0[k]); acc1[k] = fmaf(v[5].y, w1.y, acc1[k]);
            acc0[k] = fmaf(v[6].x, w1.z, acc0[k]); acc1[k] = fmaf(v[6].y, w1.z, acc1[k]);
            acc0[k] = fmaf(v[7].x, w1.w, acc0[k]); acc1[k] = fmaf(v[7].y, w1.w, acc1[k]);
        }
#pragma unroll
        for (int i = 0; i < 8; ++i) cur[i] = nxt[i];   // renamed away
    }

    float* op = Kpart + ((size_t)sub * BATCH * HWPX + (size_t)b * HWPX + px2 * 2) * NK;
#pragma unroll
    for (int kq = 0; kq < 4; ++kq)
        ((float4*)op)[kq] = make_float4(acc0[kq*4+0], acc0[kq*4+1], acc0[kq*4+2], acc0[kq*4+3]);
#pragma unroll
    for (int kq = 0; kq < 4; ++kq)
        ((float4*)op)[4+kq] = make_float4(acc1[kq*4+0], acc1[kq*4+1], acc1[kq*4+2], acc1[kq*4+3]);
}

// ---------------------------------------------------------------------------
// Kernel 1b: K = sum of 4 Kpart planes. float4 jobs, fully coalesced.
// ---------------------------------------------------------------------------
__global__ __launch_bounds__(256) void ksum(
    const float* __restrict__ Kpart, float* __restrict__ Kbuf)
{
    const int i = blockIdx.x * 256 + threadIdx.x;   // 0..401407 float4 jobs
    const float4* p = (const float4*)Kpart;
    float4 s = p[i];
#pragma unroll
    for (int s2 = 1; s2 < NSUB; ++s2) {
        const float4 v = p[(size_t)s2 * 401408 + i];
        s.x += v.x; s.y += v.y; s.z += v.z; s.w += v.w;
    }
    ((float4*)Kbuf)[i] = s;
}

// ---------------------------------------------------------------------------
// Kernel 2: P_part[b,nb,c,k] = sum_{n in 112-px slab} BN(x[b,c,n]) * K[b,n,k]
// grid: 32*28 blocks, 256 threads; thread = channel row (14 waves/CU).
// ---------------------------------------------------------------------------
__global__ __launch_bounds__(256) void kpmat(
    const float* __restrict__ x,
    const float* __restrict__ gamma, const float* __restrict__ beta,
    const float* __restrict__ mean,  const float* __restrict__ var,
    const float* __restrict__ Kbuf,  float* __restrict__ Pp)
{
    const int b  = blockIdx.x / NSLAB;
    const int nb = blockIdx.x % NSLAB;
    const int n0 = nb * 112;
    const int c  = threadIdx.x;

    const float sc = gamma[c] * rsqrtf(var[c] + EPSV);
    const float sh = fmaf(-mean[c], sc, beta[c]);

    const float4* xr = (const float4*)(x + ((size_t)b * CH + c) * HWPX + n0);
    const float*  Kp = Kbuf + ((size_t)b * HWPX + n0) * NK;

    float acc[NK];
#pragma unroll
    for (int k = 0; k < NK; ++k) acc[k] = 0.f;

#pragma unroll 4
    for (int j = 0; j < 28; ++j) {
        const float4 xv = xr[j];
        float v[4];
        v[0] = fmaf(xv.x, sc, sh); v[1] = fmaf(xv.y, sc, sh);
        v[2] = fmaf(xv.z, sc, sh); v[3] = fmaf(xv.w, sc, sh);
#pragma unroll
        for (int d = 0; d < 4; ++d) {
            const float vd = v[d];
#pragma unroll
            for (int kq = 0; kq < 4; ++kq) {
                const float4 kv = *(const float4*)(Kp + ((j*4 + d) * NK) + kq*4); // uniform
                acc[kq*4+0] = fmaf(vd, kv.x, acc[kq*4+0]);
                acc[kq*4+1] = fmaf(vd, kv.y, acc[kq*4+1]);
                acc[kq*4+2] = fmaf(vd, kv.z, acc[kq*4+2]);
                acc[kq*4+3] = fmaf(vd, kv.w, acc[kq*4+3]);
            }
        }
    }
    float4* op = (float4*)(Pp + (((size_t)b * NSLAB + nb) * CH + c) * NK);
#pragma unroll
    for (int kq = 0; kq < 4; ++kq)
        op[kq] = make_float4(acc[kq*4+0], acc[kq*4+1], acc[kq*4+2], acc[kq*4+3]);
}

// ---------------------------------------------------------------------------
// Kernel 2b: reduce slab partials Pp[b][28][CH*NK] -> P[b][CH*NK]
// ---------------------------------------------------------------------------
__global__ __launch_bounds__(256) void kpred(
    const float* __restrict__ Pp, float* __restrict__ P)
{
    const int idx = blockIdx.x * 256 + threadIdx.x;   // 32*4096 total
    const int b = idx >> 12;
    const int e = idx & 4095;
    const float* p = Pp + (size_t)b * NSLAB * 4096 + e;
    float s = 0.f;
#pragma unroll
    for (int nb = 0; nb < NSLAB; ++nb) s += p[(size_t)nb * 4096];
    P[idx] = s;
}

// ---------------------------------------------------------------------------
// Kernel 3: S = q_w @ P; attn = softmax(S/512) over k; wgt = attn @ bank.
// wgt rows padded to 52 floats (16B-aligned float4 reads in kconv).
// ---------------------------------------------------------------------------
__global__ __launch_bounds__(256) void ksoft(
    const float* __restrict__ P, const float* __restrict__ qw,
    const float* __restrict__ bank, float* __restrict__ wgt)
{
    const int b  = blockIdx.x >> 3;
    const int cb = blockIdx.x & 7;
    const int tid = threadIdx.x;

    __shared__ float s_P[CH * NK];       // full P[b] (16 KB)
    __shared__ float s_red[32 * 8 * NK]; // partial S (16 KB)
    __shared__ float s_S[32 * NK];
    __shared__ float s_attn[32 * NK];

    for (int idx = tid; idx < CH * NK; idx += 256)
        s_P[idx] = P[(size_t)b * CH * NK + idx];
    __syncthreads();

    const int c_l = tid & 31, sub = tid >> 5;
    const int c = cb * 32 + c_l;
    float a[NK];
#pragma unroll
    for (int k = 0; k < NK; ++k) a[k] = 0.f;
    const float* qrow = qw + (size_t)c * CH + sub * 32;
    for (int j = 0; j < 32; ++j) {
        const float qv = qrow[j];
        const float4* p4 = (const float4*)&s_P[(sub * 32 + j) * NK];
#pragma unroll
        for (int kq = 0; kq < 4; ++kq) {
            const float4 pv = p4[kq];
            a[kq*4+0] = fmaf(qv, pv.x, a[kq*4+0]);
            a[kq*4+1] = fmaf(qv, pv.y, a[kq*4+1]);
            a[kq*4+2] = fmaf(qv, pv.z, a[kq*4+2]);
            a[kq*4+3] = fmaf(qv, pv.w, a[kq*4+3]);
        }
    }
#pragma unroll
    for (int kq = 0; kq < 4; ++kq)
        *(float4*)&s_red[(c_l * 8 + sub) * NK + kq*4] =
            make_float4(a[kq*4+0], a[kq*4+1], a[kq*4+2], a[kq*4+3]);
    __syncthreads();

    for (int idx = tid; idx < 32 * NK; idx += 256) {
        const int cl = idx >> 4, k = idx & 15;
        float s = 0.f;
#pragma unroll
        for (int s2 = 0; s2 < 8; ++s2) s += s_red[(cl * 8 + s2) * NK + k];
        s_S[idx] = s * (1.f / 512.f);
    }
    __syncthreads();

    if (tid < 32) {
        float l[NK];
#pragma unroll
        for (int k = 0; k < NK; ++k) l[k] = s_S[tid * NK + k];
        float m = l[0];
#pragma unroll
        for (int k = 1; k < NK; ++k) m = fmaxf(m, l[k]);
        float sum = 0.f;
#pragma unroll
        for (int k = 0; k < NK; ++k) { l[k] = __expf(l[k] - m); sum += l[k]; }
        const float inv = 1.f / sum;
#pragma unroll
        for (int k = 0; k < NK; ++k) s_attn[tid * NK + k] = l[k] * inv;
    }
    __syncthreads();

    for (int idx = tid; idx < 32 * 49; idx += 256) {
        const int cl = idx / 49, e = idx - cl * 49;
        float wv = 0.f;
#pragma unroll
        for (int k = 0; k < NK; ++k)
            wv = fmaf(s_attn[cl * NK + k], bank[k * 49 + e], wv);
        wgt[((size_t)b * CH + cb * 32 + cl) * WGTS + e] = wv;
    }
}

// ---------------------------------------------------------------------------
// Kernel 4: depthwise 7x7 'same' conv — zero-LDS, shuffle-halo line buffer.
// (R10-fixed: no min-waves arg -> no VGPR cap -> no spill.)
// Slot schedule (R9-verified): reset slot j%7 at TOP of iteration j.
// ---------------------------------------------------------------------------
__global__ __launch_bounds__(256) void kconv(
    const float* __restrict__ x, const float* __restrict__ wgt,
    const float* __restrict__ bias, float* __restrict__ out)
{
    const int t  = threadIdx.x;          // 0..255
    const int pl = t >> 4;               // 0..15 local plane
    const int q  = t & 15;               // 0..15 strip slot (14 valid)
    const int qc = q < 14 ? q : 13;      // clamped col chunk for idle lanes
    const int h  = blockIdx.x & 1;       // y-half
    const int plane = (blockIdx.x >> 1) * 16 + pl;
    const int ho = h * 28;               // first output row (0 or 28; ==0 mod 7)
    const bool qlo = (q == 0), qhi = (q >= 13);
    const float bv = bias[plane & 255];

    float4 wv[13];
    const float4* wp4 = (const float4*)(wgt + (size_t)plane * WGTS);
#pragma unroll
    for (int i = 0; i < 13; ++i) wv[i] = wp4[i];
#define WTAP(idx) ((idx)%4==0 ? wv[(idx)/4].x : (idx)%4==1 ? wv[(idx)/4].y : \
                   (idx)%4==2 ? wv[(idx)/4].z : wv[(idx)/4].w)

    const float* xrow = x   + (size_t)plane * HWPX + 4 * qc;
    float*       orow = out + (size_t)plane * HWPX + 4 * qc;

    float a[7][4];
#pragma unroll
    for (int i = 0; i < 7; ++i)
#pragma unroll
        for (int ix = 0; ix < 4; ++ix) a[i][ix] = bv;

    const float4 z4 = make_float4(0.f, 0.f, 0.f, 0.f);
    int ir0 = ho - 3;
    float4 vc = (0 <= ir0 && ir0 < 56) ? *(const float4*)(xrow + ir0 * WIDTH) : z4;

#pragma unroll 7
    for (int j = 0; j < 35; ++j) {
        const int snew = j % 7;                  // static under unroll 7
#pragma unroll
        for (int ix = 0; ix < 4; ++ix) a[snew][ix] = bv;

        const int irn = ho - 3 + j + 1;
        float4 vn = (0 <= irn && irn < 56 && j + 1 < 35)
                        ? *(const float4*)(xrow + irn * WIDTH) : z4;

        float rr1 = __shfl_up(vc.y, 1), rr2 = __shfl_up(vc.z, 1), rr3 = __shfl_up(vc.w, 1);
        float rr8 = __shfl_down(vc.x, 1), rr9 = __shfl_down(vc.y, 1), rr10 = __shfl_down(vc.z, 1);
        float rr[11];
        rr[1] = qlo ? 0.f : rr1;  rr[2] = qlo ? 0.f : rr2;  rr[3] = qlo ? 0.f : rr3;
        rr[4] = vc.x; rr[5] = vc.y; rr[6] = vc.z; rr[7] = vc.w;
        rr[8] = qhi ? 0.f : rr8;  rr[9] = qhi ? 0.f : rr9;  rr[10] = qhi ? 0.f : rr10;

#pragma unroll
        for (int i = 0; i < 7; ++i) {
            const int ky = 6 - i;
            const int s  = (j + i + 1) % 7;      // static (j%7 known by unroll)
#pragma unroll
            for (int kx = 0; kx < 7; ++kx) {
                const float wk = WTAP(ky * 7 + kx);
#pragma unroll
                for (int ix = 0; ix < 4; ++ix)
                    a[s][ix] = fmaf(wk, rr[ix + kx + 1], a[s][ix]);
            }
        }

        if (j >= 6 && j < 34) {                  // output row o = ho+j-6 done
            const int o  = ho + j - 6;
            const int sd = (j + 1) % 7;          // static; next iter resets it
            if (q < 14)
                *(float4*)(orow + o * WIDTH) =
                    make_float4(a[sd][0], a[sd][1], a[sd][2], a[sd][3]);
        }
        vc = vn;
    }
#undef WTAP
}

// ---------------------------------------------------------------------------
extern "C" void kernel_launch(void* const* d_in, const int* in_sizes, int n_in,
                              void* d_out, int out_size, void* d_ws, size_t ws_size,
                              hipStream_t stream)
{
    const float* x     = (const float*)d_in[0];
    const float* gamma = (const float*)d_in[1];
    const float* beta  = (const float*)d_in[2];
    const float* mean  = (const float*)d_in[3];
    const float* var   = (const float*)d_in[4];
    const float* qw    = (const float*)d_in[5];
    const float* kw    = (const float*)d_in[6];
    const float* bank  = (const float*)d_in[7];
    const float* bias  = (const float*)d_in[8];
    float* out = (float*)d_out;

    // ws layout (34.3 MB): Kpart is dead after ksum, so Pp aliases it.
    float* ws    = (float*)d_ws;
    float* Kpart = ws;                                   // 4*32*3136*16 = 6,422,528 f
    float* Pp    = ws;                                   // alias: 32*28*4096 = 3,670,016 f
    float* Kbuf  = ws + (size_t)NSUB * BATCH * HWPX * NK;   // 1,605,632 f
    float* P     = Kbuf + (size_t)BATCH * HWPX * NK;        //   131,072 f
    float* wgt   = P + (size_t)BATCH * CH * NK;             // 8192*52 = 425,984 f

    kkvec<<<dim3(NSUB * 196),   dim3(256), 0, stream>>>(x, gamma, beta, mean, var, kw, Kpart);
    ksum <<<dim3(1568),         dim3(256), 0, stream>>>(Kpart, Kbuf);
    kpmat<<<dim3(BATCH * NSLAB),dim3(256), 0, stream>>>(x, gamma, beta, mean, var, Kbuf, Pp);
    kpred<<<dim3(512),          dim3(256), 0, stream>>>(Pp, P);
    ksoft<<<dim3(BATCH * 8),    dim3(256), 0, stream>>>(P, qw, bank, wgt);
    kconv<<<dim3(BATCH * CH / 8), dim3(256), 0, stream>>>(x, wgt, bias, out);
}

// Round 14
// 137.237 us; speedup vs baseline: 1.2836x; 1.1014x over previous
//
#include <hip/hip_runtime.h>

#define BATCH 32
#define CH    256
#define HWPX  3136   // 56*56
#define WIDTH 56
#define NK    16
#define NSLAB 28     // kpmat pixel slabs per batch (112 px each)
#define NSUB  4      // kkvec channel split (NS=8 broke L3 residency, R12)
#define WGTS  52     // wgt row stride (49 padded to 13*float4)
#define EPSV  1e-5f

// ---------------------------------------------------------------------------
// Kernel 1: K-partials. Kpart[s][b,n,k] = sum_{c in sub s} k_w[k,c]*BN(x[b,c,n])
// R12: NS=8 broke L3 residency (3.2x write amp). R13: explicit dbuf raised
// VGPR 40->84, occupancy 29->21%, 61->80us — compiler already pipelines.
// R14: keep R11 body, shrink blocks to 1 wave (64 thr), grid 3136 = 12.25
// blocks/CU. Fixes the 784-block tail (784 = 3x256+16: 16 CUs ran a 4th
// ~20us block) and quadruples resident waves -> ~50KB/CU loads in flight.
// ---------------------------------------------------------------------------
__global__ __launch_bounds__(64) void kkvec(
    const float* __restrict__ x,
    const float* __restrict__ gamma, const float* __restrict__ beta,
    const float* __restrict__ mean,  const float* __restrict__ var,
    const float* __restrict__ kw,    float* __restrict__ Kpart)
{
    const int sub = blockIdx.x / 784;           // 0..3, block-uniform
    const int pb  = blockIdx.x % 784;
    const int job = pb * 64 + threadIdx.x;      // 0..50175 = b*1568 + px2
    const int b   = job / 1568;
    const int px2 = job % 1568;                 // float2 index in plane
    const int cbase = sub * 64;
    const float* xp = x + ((size_t)b * CH + cbase) * HWPX + px2 * 2;

    float acc0[NK], acc1[NK];
#pragma unroll
    for (int k = 0; k < NK; ++k) { acc0[k] = 0.f; acc1[k] = 0.f; }

    for (int c0 = 0; c0 < 64; c0 += 8) {
        float2 v[8];
#pragma unroll
        for (int i = 0; i < 8; ++i)             // 8 x 512B wave-loads in flight
            v[i] = *(const float2*)(xp + (size_t)(c0 + i) * HWPX);
#pragma unroll
        for (int i = 0; i < 8; ++i) {           // BN (params wave-uniform)
            const int c = cbase + c0 + i;
            const float sc = gamma[c] * rsqrtf(var[c] + EPSV);
            const float sh = fmaf(-mean[c], sc, beta[c]);
            v[i].x = fmaf(v[i].x, sc, sh);
            v[i].y = fmaf(v[i].y, sc, sh);
        }
#pragma unroll
        for (int k = 0; k < NK; ++k) {
            const float4 w0 = *(const float4*)(kw + k * CH + cbase + c0);     // uniform
            const float4 w1 = *(const float4*)(kw + k * CH + cbase + c0 + 4); // uniform
            acc0[k] = fmaf(v[0].x, w0.x, acc0[k]); acc1[k] = fmaf(v[0].y, w0.x, acc1[k]);
            acc0[k] = fmaf(v[1].x, w0.y, acc0[k]); acc1[k] = fmaf(v[1].y, w0.y, acc1[k]);
            acc0[k] = fmaf(v[2].x, w0.z, acc0[k]); acc1[k] = fmaf(v[2].y, w0.z, acc1[k]);
            acc0[k] = fmaf(v[3].x, w0.w, acc0[k]); acc1[k] = fmaf(v[3].y, w0.w, acc1[k]);
            acc0[k] = fmaf(v[4].x, w1.x, acc0[k]); acc1[k] = fmaf(v[4].y, w1.x, acc1[k]);
            acc0[k] = fmaf(v[5].x, w1.y, acc0[k]); acc1[k] = fmaf(v[5].y, w1.y, acc1[k]);
            acc0[k] = fmaf(v[6].x, w1.z, acc0[k]); acc1[k] = fmaf(v[6].y, w1.z, acc1[k]);
            acc0[k] = fmaf(v[7].x, w1.w, acc0[k]); acc1[k] = fmaf(v[7].y, w1.w, acc1[k]);
        }
    }

    float* op = Kpart + ((size_t)sub * BATCH * HWPX + (size_t)b * HWPX + px2 * 2) * NK;
#pragma unroll
    for (int kq = 0; kq < 4; ++kq)
        ((float4*)op)[kq] = make_float4(acc0[kq*4+0], acc0[kq*4+1], acc0[kq*4+2], acc0[kq*4+3]);
#pragma unroll
    for (int kq = 0; kq < 4; ++kq)
        ((float4*)op)[4+kq] = make_float4(acc1[kq*4+0], acc1[kq*4+1], acc1[kq*4+2], acc1[kq*4+3]);
}

// ---------------------------------------------------------------------------
// Kernel 1b: K = sum of 4 Kpart planes. float4 jobs, fully coalesced.
// ---------------------------------------------------------------------------
__global__ __launch_bounds__(256) void ksum(
    const float* __restrict__ Kpart, float* __restrict__ Kbuf)
{
    const int i = blockIdx.x * 256 + threadIdx.x;   // 0..401407 float4 jobs
    const float4* p = (const float4*)Kpart;
    float4 s = p[i];
#pragma unroll
    for (int s2 = 1; s2 < NSUB; ++s2) {
        const float4 v = p[(size_t)s2 * 401408 + i];
        s.x += v.x; s.y += v.y; s.z += v.z; s.w += v.w;
    }
    ((float4*)Kbuf)[i] = s;
}

// ---------------------------------------------------------------------------
// Kernel 2: P_part[b,nb,c,k] = sum_{n in 112-px slab} BN(x[b,c,n]) * K[b,n,k]
// grid: 32*28 blocks, 256 threads; thread = channel row (14 waves/CU).
// ---------------------------------------------------------------------------
__global__ __launch_bounds__(256) void kpmat(
    const float* __restrict__ x,
    const float* __restrict__ gamma, const float* __restrict__ beta,
    const float* __restrict__ mean,  const float* __restrict__ var,
    const float* __restrict__ Kbuf,  float* __restrict__ Pp)
{
    const int b  = blockIdx.x / NSLAB;
    const int nb = blockIdx.x % NSLAB;
    const int n0 = nb * 112;
    const int c  = threadIdx.x;

    const float sc = gamma[c] * rsqrtf(var[c] + EPSV);
    const float sh = fmaf(-mean[c], sc, beta[c]);

    const float4* xr = (const float4*)(x + ((size_t)b * CH + c) * HWPX + n0);
    const float*  Kp = Kbuf + ((size_t)b * HWPX + n0) * NK;

    float acc[NK];
#pragma unroll
    for (int k = 0; k < NK; ++k) acc[k] = 0.f;

#pragma unroll 4
    for (int j = 0; j < 28; ++j) {
        const float4 xv = xr[j];
        float v[4];
        v[0] = fmaf(xv.x, sc, sh); v[1] = fmaf(xv.y, sc, sh);
        v[2] = fmaf(xv.z, sc, sh); v[3] = fmaf(xv.w, sc, sh);
#pragma unroll
        for (int d = 0; d < 4; ++d) {
            const float vd = v[d];
#pragma unroll
            for (int kq = 0; kq < 4; ++kq) {
                const float4 kv = *(const float4*)(Kp + ((j*4 + d) * NK) + kq*4); // uniform
                acc[kq*4+0] = fmaf(vd, kv.x, acc[kq*4+0]);
                acc[kq*4+1] = fmaf(vd, kv.y, acc[kq*4+1]);
                acc[kq*4+2] = fmaf(vd, kv.z, acc[kq*4+2]);
                acc[kq*4+3] = fmaf(vd, kv.w, acc[kq*4+3]);
            }
        }
    }
    float4* op = (float4*)(Pp + (((size_t)b * NSLAB + nb) * CH + c) * NK);
#pragma unroll
    for (int kq = 0; kq < 4; ++kq)
        op[kq] = make_float4(acc[kq*4+0], acc[kq*4+1], acc[kq*4+2], acc[kq*4+3]);
}

// ---------------------------------------------------------------------------
// Kernel 2b: reduce slab partials Pp[b][28][CH*NK] -> P[b][CH*NK]
// ---------------------------------------------------------------------------
__global__ __launch_bounds__(256) void kpred(
    const float* __restrict__ Pp, float* __restrict__ P)
{
    const int idx = blockIdx.x * 256 + threadIdx.x;   // 32*4096 total
    const int b = idx >> 12;
    const int e = idx & 4095;
    const float* p = Pp + (size_t)b * NSLAB * 4096 + e;
    float s = 0.f;
#pragma unroll
    for (int nb = 0; nb < NSLAB; ++nb) s += p[(size_t)nb * 4096];
    P[idx] = s;
}

// ---------------------------------------------------------------------------
// Kernel 3: S = q_w @ P; attn = softmax(S/512) over k; wgt = attn @ bank.
// wgt rows padded to 52 floats (16B-aligned float4 reads in kconv).
// ---------------------------------------------------------------------------
__global__ __launch_bounds__(256) void ksoft(
    const float* __restrict__ P, const float* __restrict__ qw,
    const float* __restrict__ bank, float* __restrict__ wgt)
{
    const int b  = blockIdx.x >> 3;
    const int cb = blockIdx.x & 7;
    const int tid = threadIdx.x;

    __shared__ float s_P[CH * NK];       // full P[b] (16 KB)
    __shared__ float s_red[32 * 8 * NK]; // partial S (16 KB)
    __shared__ float s_S[32 * NK];
    __shared__ float s_attn[32 * NK];

    for (int idx = tid; idx < CH * NK; idx += 256)
        s_P[idx] = P[(size_t)b * CH * NK + idx];
    __syncthreads();

    const int c_l = tid & 31, sub = tid >> 5;
    const int c = cb * 32 + c_l;
    float a[NK];
#pragma unroll
    for (int k = 0; k < NK; ++k) a[k] = 0.f;
    const float* qrow = qw + (size_t)c * CH + sub * 32;
    for (int j = 0; j < 32; ++j) {
        const float qv = qrow[j];
        const float4* p4 = (const float4*)&s_P[(sub * 32 + j) * NK];
#pragma unroll
        for (int kq = 0; kq < 4; ++kq) {
            const float4 pv = p4[kq];
            a[kq*4+0] = fmaf(qv, pv.x, a[kq*4+0]);
            a[kq*4+1] = fmaf(qv, pv.y, a[kq*4+1]);
            a[kq*4+2] = fmaf(qv, pv.z, a[kq*4+2]);
            a[kq*4+3] = fmaf(qv, pv.w, a[kq*4+3]);
        }
    }
#pragma unroll
    for (int kq = 0; kq < 4; ++kq)
        *(float4*)&s_red[(c_l * 8 + sub) * NK + kq*4] =
            make_float4(a[kq*4+0], a[kq*4+1], a[kq*4+2], a[kq*4+3]);
    __syncthreads();

    for (int idx = tid; idx < 32 * NK; idx += 256) {
        const int cl = idx >> 4, k = idx & 15;
        float s = 0.f;
#pragma unroll
        for (int s2 = 0; s2 < 8; ++s2) s += s_red[(cl * 8 + s2) * NK + k];
        s_S[idx] = s * (1.f / 512.f);
    }
    __syncthreads();

    if (tid < 32) {
        float l[NK];
#pragma unroll
        for (int k = 0; k < NK; ++k) l[k] = s_S[tid * NK + k];
        float m = l[0];
#pragma unroll
        for (int k = 1; k < NK; ++k) m = fmaxf(m, l[k]);
        float sum = 0.f;
#pragma unroll
        for (int k = 0; k < NK; ++k) { l[k] = __expf(l[k] - m); sum += l[k]; }
        const float inv = 1.f / sum;
#pragma unroll
        for (int k = 0; k < NK; ++k) s_attn[tid * NK + k] = l[k] * inv;
    }
    __syncthreads();

    for (int idx = tid; idx < 32 * 49; idx += 256) {
        const int cl = idx / 49, e = idx - cl * 49;
        float wv = 0.f;
#pragma unroll
        for (int k = 0; k < NK; ++k)
            wv = fmaf(s_attn[cl * NK + k], bank[k * 49 + e], wv);
        wgt[((size_t)b * CH + cb * 32 + cl) * WGTS + e] = wv;
    }
}

// ---------------------------------------------------------------------------
// Kernel 4: depthwise 7x7 'same' conv — zero-LDS, shuffle-halo line buffer.
// (R10-fixed: no min-waves arg -> no VGPR cap -> no spill.)
// Slot schedule (R9-verified): reset slot j%7 at TOP of iteration j.
// ---------------------------------------------------------------------------
__global__ __launch_bounds__(256) void kconv(
    const float* __restrict__ x, const float* __restrict__ wgt,
    const float* __restrict__ bias, float* __restrict__ out)
{
    const int t  = threadIdx.x;          // 0..255
    const int pl = t >> 4;               // 0..15 local plane
    const int q  = t & 15;               // 0..15 strip slot (14 valid)
    const int qc = q < 14 ? q : 13;      // clamped col chunk for idle lanes
    const int h  = blockIdx.x & 1;       // y-half
    const int plane = (blockIdx.x >> 1) * 16 + pl;
    const int ho = h * 28;               // first output row (0 or 28; ==0 mod 7)
    const bool qlo = (q == 0), qhi = (q >= 13);
    const float bv = bias[plane & 255];

    float4 wv[13];
    const float4* wp4 = (const float4*)(wgt + (size_t)plane * WGTS);
#pragma unroll
    for (int i = 0; i < 13; ++i) wv[i] = wp4[i];
#define WTAP(idx) ((idx)%4==0 ? wv[(idx)/4].x : (idx)%4==1 ? wv[(idx)/4].y : \
                   (idx)%4==2 ? wv[(idx)/4].z : wv[(idx)/4].w)

    const float* xrow = x   + (size_t)plane * HWPX + 4 * qc;
    float*       orow = out + (size_t)plane * HWPX + 4 * qc;

    float a[7][4];
#pragma unroll
    for (int i = 0; i < 7; ++i)
#pragma unroll
        for (int ix = 0; ix < 4; ++ix) a[i][ix] = bv;

    const float4 z4 = make_float4(0.f, 0.f, 0.f, 0.f);
    int ir0 = ho - 3;
    float4 vc = (0 <= ir0 && ir0 < 56) ? *(const float4*)(xrow + ir0 * WIDTH) : z4;

#pragma unroll 7
    for (int j = 0; j < 35; ++j) {
        const int snew = j % 7;                  // static under unroll 7
#pragma unroll
        for (int ix = 0; ix < 4; ++ix) a[snew][ix] = bv;

        const int irn = ho - 3 + j + 1;
        float4 vn = (0 <= irn && irn < 56 && j + 1 < 35)
                        ? *(const float4*)(xrow + irn * WIDTH) : z4;

        float rr1 = __shfl_up(vc.y, 1), rr2 = __shfl_up(vc.z, 1), rr3 = __shfl_up(vc.w, 1);
        float rr8 = __shfl_down(vc.x, 1), rr9 = __shfl_down(vc.y, 1), rr10 = __shfl_down(vc.z, 1);
        float rr[11];
        rr[1] = qlo ? 0.f : rr1;  rr[2] = qlo ? 0.f : rr2;  rr[3] = qlo ? 0.f : rr3;
        rr[4] = vc.x; rr[5] = vc.y; rr[6] = vc.z; rr[7] = vc.w;
        rr[8] = qhi ? 0.f : rr8;  rr[9] = qhi ? 0.f : rr9;  rr[10] = qhi ? 0.f : rr10;

#pragma unroll
        for (int i = 0; i < 7; ++i) {
            const int ky = 6 - i;
            const int s  = (j + i + 1) % 7;      // static (j%7 known by unroll)
#pragma unroll
            for (int kx = 0; kx < 7; ++kx) {
                const float wk = WTAP(ky * 7 + kx);
#pragma unroll
                for (int ix = 0; ix < 4; ++ix)
                    a[s][ix] = fmaf(wk, rr[ix + kx + 1], a[s][ix]);
            }
        }

        if (j >= 6 && j < 34) {                  // output row o = ho+j-6 done
            const int o  = ho + j - 6;
            const int sd = (j + 1) % 7;          // static; next iter resets it
            if (q < 14)
                *(float4*)(orow + o * WIDTH) =
                    make_float4(a[sd][0], a[sd][1], a[sd][2], a[sd][3]);
        }
        vc = vn;
    }
#undef WTAP
}

// ---------------------------------------------------------------------------
extern "C" void kernel_launch(void* const* d_in, const int* in_sizes, int n_in,
                              void* d_out, int out_size, void* d_ws, size_t ws_size,
                              hipStream_t stream)
{
    const float* x     = (const float*)d_in[0];
    const float* gamma = (const float*)d_in[1];
    const float* beta  = (const float*)d_in[2];
    const float* mean  = (const float*)d_in[3];
    const float* var   = (const float*)d_in[4];
    const float* qw    = (const float*)d_in[5];
    const float* kw    = (const float*)d_in[6];
    const float* bank  = (const float*)d_in[7];
    const float* bias  = (const float*)d_in[8];
    float* out = (float*)d_out;

    // ws layout (34.3 MB): Kpart is dead after ksum, so Pp aliases it.
    float* ws    = (float*)d_ws;
    float* Kpart = ws;                                   // 4*32*3136*16 = 6,422,528 f
    float* Pp    = ws;                                   // alias: 32*28*4096 = 3,670,016 f
    float* Kbuf  = ws + (size_t)NSUB * BATCH * HWPX * NK;   // 1,605,632 f
    float* P     = Kbuf + (size_t)BATCH * HWPX * NK;        //   131,072 f
    float* wgt   = P + (size_t)BATCH * CH * NK;             // 8192*52 = 425,984 f

    kkvec<<<dim3(NSUB * 784),   dim3(64),  0, stream>>>(x, gamma, beta, mean, var, kw, Kpart);
    ksum <<<dim3(1568),         dim3(256), 0, stream>>>(Kpart, Kbuf);
    kpmat<<<dim3(BATCH * NSLAB),dim3(256), 0, stream>>>(x, gamma, beta, mean, var, Kbuf, Pp);
    kpred<<<dim3(512),          dim3(256), 0, stream>>>(Pp, P);
    ksoft<<<dim3(BATCH * 8),    dim3(256), 0, stream>>>(P, qw, bank, wgt);
    kconv<<<dim3(BATCH * CH / 8), dim3(256), 0, stream>>>(x, wgt, bias, out);
}